// Round 3
// baseline (121.225 us; speedup 1.0000x reference)
//
#include <hip/hip_runtime.h>

#define NN      4096   // total nodes
#define BG      64     // graphs
#define NPG_    64     // nodes per graph
#define LT_     128
#define LL_     32
#define D_      256
#define OUT_    1024
#define PNPB    8      // nodes per block (proj kernel)

// ---------------- Kernel A: ragged gathers, 1 node/block, ids staged in LDS ----------------
__global__ __launch_bounds__(256) void gather_kernel(
    const int*   __restrict__ text_ids,
    const int*   __restrict__ label_ids,
    const int*   __restrict__ text_len,
    const int*   __restrict__ label_len,
    const float* __restrict__ word_emb,
    const float* __restrict__ label_emb,
    float*       __restrict__ text_out,   // [NN, D]
    float*       __restrict__ label_out)  // [NN, D]
{
    __shared__ int   sIds[LT_ + LL_];
    __shared__ float redT[4][D_];
    __shared__ float redL[4][D_];

    const int n    = blockIdx.x;
    const int tid  = threadIdx.x;
    const int wave = tid >> 6;
    const int lane = tid & 63;

    // stage all ids (coalesced, one shot)
    if (tid < LT_)               sIds[tid] = text_ids [(size_t)n * LT_ + tid];
    else if (tid < LT_ + LL_)    sIds[tid] = label_ids[(size_t)n * LL_ + (tid - LT_)];
    const int lt = text_len[n];
    const int ll = label_len[n];
    __syncthreads();

    float4 aT = make_float4(0.f, 0.f, 0.f, 0.f);
    float4 aL = make_float4(0.f, 0.f, 0.f, 0.f);

    {   // text partial sum: wave w takes l = w, w+4, ...
        const float* __restrict__ bp = word_emb + (size_t)lane * 4;
        #pragma unroll 8
        for (int l = wave; l < lt; l += 4) {
            const float4 v = *reinterpret_cast<const float4*>(bp + (size_t)sIds[l] * D_);
            aT.x += v.x; aT.y += v.y; aT.z += v.z; aT.w += v.w;
        }
    }
    {   // label partial sum
        const float* __restrict__ bp = label_emb + (size_t)lane * 4;
        #pragma unroll 8
        for (int l = wave; l < ll; l += 4) {
            const float4 v = *reinterpret_cast<const float4*>(bp + (size_t)sIds[LT_ + l] * D_);
            aL.x += v.x; aL.y += v.y; aL.z += v.z; aL.w += v.w;
        }
    }

    // deferred partial-sum writes (single drain point)
    *reinterpret_cast<float4*>(&redT[wave][lane * 4]) = aT;
    *reinterpret_cast<float4*>(&redL[wave][lane * 4]) = aL;
    __syncthreads();

    // cross-wave reduce, column = tid (fixed order -> deterministic)
    const float t  = (redT[0][tid] + redT[1][tid]) + (redT[2][tid] + redT[3][tid]);
    const float lv = (redL[0][tid] + redL[1][tid]) + (redL[2][tid] + redL[3][tid]);
    text_out [(size_t)n * D_ + tid] = t / (float)lt;
    label_out[(size_t)n * D_ + tid] = lv;
}

// ---------------- Kernel B: batched projection, register-tiled 2 nodes x 4 cols ----------------
__global__ __launch_bounds__(256) void proj_kernel(
    const float* __restrict__ text_out,   // [NN, D]
    const float* __restrict__ label_out,  // [NN, D]
    const float* __restrict__ Wg_text,
    const float* __restrict__ Wg_label,
    const float* __restrict__ w_adap,
    float*       __restrict__ h_comb)     // [NN, D] (may alias text_out)
{
    __shared__ float xT[PNPB][D_ + 4];    // +4 pad: node rows land on distinct banks
    __shared__ float xL[PNPB][D_ + 4];

    const int tid  = threadIdx.x;
    const int wave = tid >> 6;      // wave owns cols [wave*64, wave*64+64)
    const int lane = tid & 63;
    const int ng   = lane >> 4;     // node pair: nodes ng*2, ng*2+1
    const int cw   = lane & 15;     // col quad within the wave's slice
    const int c0   = wave * 64 + cw * 4;
    const int base = blockIdx.x * PNPB;

    // stage x (coalesced float4)
    for (int idx = tid; idx < PNPB * (D_ / 4); idx += 256) {
        const int nd = idx >> 6;
        const int dd = (idx & 63) * 4;
        *reinterpret_cast<float4*>(&xT[nd][dd]) =
            *reinterpret_cast<const float4*>(text_out  + (size_t)(base + nd) * D_ + dd);
        *reinterpret_cast<float4*>(&xL[nd][dd]) =
            *reinterpret_cast<const float4*>(label_out + (size_t)(base + nd) * D_ + dd);
    }
    __syncthreads();

    const int n0 = ng * 2;
    float aT[2][4] = {{0.f,0.f,0.f,0.f},{0.f,0.f,0.f,0.f}};
    float aL[2][4] = {{0.f,0.f,0.f,0.f},{0.f,0.f,0.f,0.f}};

    for (int d4 = 0; d4 < D_; d4 += 4) {
        const float4 xt0 = *reinterpret_cast<const float4*>(&xT[n0    ][d4]);
        const float4 xt1 = *reinterpret_cast<const float4*>(&xT[n0 + 1][d4]);
        const float4 xl0 = *reinterpret_cast<const float4*>(&xL[n0    ][d4]);
        const float4 xl1 = *reinterpret_cast<const float4*>(&xL[n0 + 1][d4]);
        const float xt0a[4] = {xt0.x, xt0.y, xt0.z, xt0.w};
        const float xt1a[4] = {xt1.x, xt1.y, xt1.z, xt1.w};
        const float xl0a[4] = {xl0.x, xl0.y, xl0.z, xl0.w};
        const float xl1a[4] = {xl1.x, xl1.y, xl1.z, xl1.w};
        #pragma unroll
        for (int k = 0; k < 4; ++k) {
            const float4 wt = *reinterpret_cast<const float4*>(
                Wg_text  + (size_t)(d4 + k) * D_ + c0);
            const float4 wl = *reinterpret_cast<const float4*>(
                Wg_label + (size_t)(d4 + k) * D_ + c0);
            aT[0][0] = fmaf(xt0a[k], wt.x, aT[0][0]);
            aT[0][1] = fmaf(xt0a[k], wt.y, aT[0][1]);
            aT[0][2] = fmaf(xt0a[k], wt.z, aT[0][2]);
            aT[0][3] = fmaf(xt0a[k], wt.w, aT[0][3]);
            aT[1][0] = fmaf(xt1a[k], wt.x, aT[1][0]);
            aT[1][1] = fmaf(xt1a[k], wt.y, aT[1][1]);
            aT[1][2] = fmaf(xt1a[k], wt.z, aT[1][2]);
            aT[1][3] = fmaf(xt1a[k], wt.w, aT[1][3]);
            aL[0][0] = fmaf(xl0a[k], wl.x, aL[0][0]);
            aL[0][1] = fmaf(xl0a[k], wl.y, aL[0][1]);
            aL[0][2] = fmaf(xl0a[k], wl.z, aL[0][2]);
            aL[0][3] = fmaf(xl0a[k], wl.w, aL[0][3]);
            aL[1][0] = fmaf(xl1a[k], wl.x, aL[1][0]);
            aL[1][1] = fmaf(xl1a[k], wl.y, aL[1][1]);
            aL[1][2] = fmaf(xl1a[k], wl.z, aL[1][2]);
            aL[1][3] = fmaf(xl1a[k], wl.w, aL[1][3]);
        }
    }

    const float w0 = w_adap[0] * (1.0f / (float)NPG_);
    const float w1 = w_adap[1] * (1.0f / (float)NPG_);
    #pragma unroll
    for (int nd = 0; nd < 2; ++nd) {
        float4 r;
        r.x = w0 * (aT[nd][0] > 0.f ? aT[nd][0] : 0.f) + w1 * (aL[nd][0] > 0.f ? aL[nd][0] : 0.f);
        r.y = w0 * (aT[nd][1] > 0.f ? aT[nd][1] : 0.f) + w1 * (aL[nd][1] > 0.f ? aL[nd][1] : 0.f);
        r.z = w0 * (aT[nd][2] > 0.f ? aT[nd][2] : 0.f) + w1 * (aL[nd][2] > 0.f ? aL[nd][2] : 0.f);
        r.w = w0 * (aT[nd][3] > 0.f ? aT[nd][3] : 0.f) + w1 * (aL[nd][3] > 0.f ? aL[nd][3] : 0.f);
        *reinterpret_cast<float4*>(h_comb + (size_t)(base + n0 + nd) * D_ + c0) = r;
    }
}

// ---------------- Kernel C: per-graph readout + MLP, 4 blocks per graph split Wout ----------------
__global__ __launch_bounds__(256) void graph_kernel(
    const float* __restrict__ h_comb,   // [NN, D]
    const float* __restrict__ W1,       // [D, D]
    const float* __restrict__ b1,       // [D]
    const float* __restrict__ Wout,     // [D, OUT]
    const float* __restrict__ bout,     // [OUT]
    float*       __restrict__ out)      // [BG, OUT]
{
    __shared__ float fused[D_];
    __shared__ float hrow[D_];

    const int bx   = blockIdx.x;
    const int b    = bx >> 2;
    const int part = bx & 3;
    const int tid  = threadIdx.x;

    // segment sum over the 64 nodes of this graph (scaling already applied)
    float acc = 0.f;
    const float* __restrict__ basep = h_comb + (size_t)b * NPG_ * D_ + tid;
    #pragma unroll 8
    for (int n = 0; n < NPG_; ++n) acc += basep[(size_t)n * D_];
    fused[tid] = acc;
    __syncthreads();

    // h = relu(fused @ W1 + b1)   (redundant across the 4 sibling blocks; cheap)
    float a1 = b1[tid];
    for (int d = 0; d < D_; ++d)
        a1 = fmaf(fused[d], W1[(size_t)d * D_ + tid], a1);
    hrow[tid] = a1 > 0.f ? a1 : 0.f;
    __syncthreads();

    // out column j = part*256 + tid
    const int j = part * 256 + tid;
    float o = bout[j];
    for (int d = 0; d < D_; ++d)
        o = fmaf(hrow[d], Wout[(size_t)d * OUT_ + j], o);
    out[(size_t)b * OUT_ + j] = o;
}

extern "C" void kernel_launch(void* const* d_in, const int* in_sizes, int n_in,
                              void* d_out, int out_size, void* d_ws, size_t ws_size,
                              hipStream_t stream) {
    const int*   text_ids  = (const int*)  d_in[0];
    const int*   label_ids = (const int*)  d_in[1];
    const int*   text_len  = (const int*)  d_in[2];
    const int*   label_len = (const int*)  d_in[3];
    const float* word_emb  = (const float*)d_in[4];
    const float* label_emb = (const float*)d_in[5];
    const float* Wg_text   = (const float*)d_in[6];
    const float* Wg_label  = (const float*)d_in[7];
    const float* w_adap    = (const float*)d_in[8];
    const float* W1        = (const float*)d_in[9];
    const float* b1        = (const float*)d_in[10];
    const float* Wout      = (const float*)d_in[11];
    const float* bout      = (const float*)d_in[12];

    // ws layout: [0, 4MB) text_out (reused as h_comb), [4MB, 8MB) label_out
    float* text_out  = (float*)d_ws;
    float* label_out = text_out + (size_t)NN * D_;
    float* h_comb    = text_out;   // alias: proj stages x in LDS before overwriting
    float* out       = (float*)d_out;

    gather_kernel<<<NN, 256, 0, stream>>>(
        text_ids, label_ids, text_len, label_len,
        word_emb, label_emb, text_out, label_out);

    proj_kernel<<<NN / PNPB, 256, 0, stream>>>(
        text_out, label_out, Wg_text, Wg_label, w_adap, h_comb);

    graph_kernel<<<BG * 4, 256, 0, stream>>>(
        h_comb, W1, b1, Wout, bout, out);
}

// Round 4
// 96.139 us; speedup vs baseline: 1.2609x; 1.2609x over previous
//
#include <hip/hip_runtime.h>

#define NN      4096   // total nodes
#define BG      64     // graphs
#define NPG_    64     // nodes per graph
#define LT_     128
#define LL_     32
#define D_      256
#define OUT_    1024

// ---------------- Kernel A: ragged gathers, 1 node/block, ids staged in LDS ----------------
__global__ __launch_bounds__(256) void gather_kernel(
    const int*   __restrict__ text_ids,
    const int*   __restrict__ label_ids,
    const int*   __restrict__ text_len,
    const int*   __restrict__ label_len,
    const float* __restrict__ word_emb,
    const float* __restrict__ label_emb,
    float*       __restrict__ text_out,   // [NN, D]
    float*       __restrict__ label_out)  // [NN, D]
{
    __shared__ int   sIds[LT_ + LL_];
    __shared__ float redT[4][D_];
    __shared__ float redL[4][D_];

    const int n    = blockIdx.x;
    const int tid  = threadIdx.x;
    const int wave = tid >> 6;
    const int lane = tid & 63;

    if (tid < LT_)               sIds[tid] = text_ids [(size_t)n * LT_ + tid];
    else if (tid < LT_ + LL_)    sIds[tid] = label_ids[(size_t)n * LL_ + (tid - LT_)];
    const int lt = text_len[n];
    const int ll = label_len[n];
    __syncthreads();

    float4 aT = make_float4(0.f, 0.f, 0.f, 0.f);
    float4 aL = make_float4(0.f, 0.f, 0.f, 0.f);

    {   // text partial sum: wave w takes l = w, w+4, ...
        const float* __restrict__ bp = word_emb + (size_t)lane * 4;
        #pragma unroll 8
        for (int l = wave; l < lt; l += 4) {
            const float4 v = *reinterpret_cast<const float4*>(bp + (size_t)sIds[l] * D_);
            aT.x += v.x; aT.y += v.y; aT.z += v.z; aT.w += v.w;
        }
    }
    {   // label partial sum
        const float* __restrict__ bp = label_emb + (size_t)lane * 4;
        #pragma unroll 8
        for (int l = wave; l < ll; l += 4) {
            const float4 v = *reinterpret_cast<const float4*>(bp + (size_t)sIds[LT_ + l] * D_);
            aL.x += v.x; aL.y += v.y; aL.z += v.z; aL.w += v.w;
        }
    }

    *reinterpret_cast<float4*>(&redT[wave][lane * 4]) = aT;
    *reinterpret_cast<float4*>(&redL[wave][lane * 4]) = aL;
    __syncthreads();

    const float t  = (redT[0][tid] + redT[1][tid]) + (redT[2][tid] + redT[3][tid]);
    const float lv = (redL[0][tid] + redL[1][tid]) + (redL[2][tid] + redL[3][tid]);
    text_out [(size_t)n * D_ + tid] = t / (float)lt;
    label_out[(size_t)n * D_ + tid] = lv;
}

// ---------------- Kernel B: k-split register-tiled projection ----------------
// Block: 8 nodes x 256 cols. Wave w owns k-slice [w*64, w*64+64).
// Lane tile: 4 nodes (ng) x 8 cols (cg) x 2 matrices. Partials reduced via LDS.
__global__ __launch_bounds__(256) void proj_kernel(
    const float* __restrict__ text_out,   // [NN, D]
    const float* __restrict__ label_out,  // [NN, D]
    const float* __restrict__ Wg_text,
    const float* __restrict__ Wg_label,
    const float* __restrict__ w_adap,
    float*       __restrict__ h_comb)     // [NN, D] (may alias text_out; rows disjoint per block)
{
    __shared__ float xT[8][264];     // +8 pad keeps rows bank-shifted
    __shared__ float xL[8][264];
    __shared__ float red[4][2048];   // per-wave partials, one matrix at a time

    const int tid  = threadIdx.x;
    const int wave = tid >> 6;
    const int lane = tid & 63;
    const int cg   = lane & 31;      // col group: cols cg*8 .. cg*8+7
    const int ng   = lane >> 5;      // node group: nodes ng*4 .. ng*4+3
    const int base = blockIdx.x * 8;
    const int c0   = cg * 8;

    // stage x tiles (coalesced float4, conflict-free b128 writes)
    for (int idx = tid; idx < 8 * 64; idx += 256) {
        const int nd = idx >> 6;
        const int k4 = (idx & 63) << 2;
        *reinterpret_cast<float4*>(&xT[nd][k4]) =
            *reinterpret_cast<const float4*>(text_out  + (size_t)(base + nd) * D_ + k4);
        *reinterpret_cast<float4*>(&xL[nd][k4]) =
            *reinterpret_cast<const float4*>(label_out + (size_t)(base + nd) * D_ + k4);
    }
    __syncthreads();

    float aT[4][8], aL[4][8];
    #pragma unroll
    for (int i = 0; i < 4; ++i) {
        #pragma unroll
        for (int j = 0; j < 8; ++j) { aT[i][j] = 0.f; aL[i][j] = 0.f; }
    }

    const int kbase = wave * 64;
    const float* __restrict__ wtp = Wg_text  + c0;
    const float* __restrict__ wlp = Wg_label + c0;

    for (int kk = 0; kk < 64; kk += 4) {
        const int k = kbase + kk;
        float xt[4][4], xl[4][4];
        #pragma unroll
        for (int i = 0; i < 4; ++i) {
            const float4 a = *reinterpret_cast<const float4*>(&xT[ng * 4 + i][k]);
            const float4 b = *reinterpret_cast<const float4*>(&xL[ng * 4 + i][k]);
            xt[i][0] = a.x; xt[i][1] = a.y; xt[i][2] = a.z; xt[i][3] = a.w;
            xl[i][0] = b.x; xl[i][1] = b.y; xl[i][2] = b.z; xl[i][3] = b.w;
        }
        #pragma unroll
        for (int dk = 0; dk < 4; ++dk) {
            const size_t ro = (size_t)(k + dk) * D_;
            const float4 wt0 = *reinterpret_cast<const float4*>(wtp + ro);
            const float4 wt1 = *reinterpret_cast<const float4*>(wtp + ro + 4);
            const float4 wl0 = *reinterpret_cast<const float4*>(wlp + ro);
            const float4 wl1 = *reinterpret_cast<const float4*>(wlp + ro + 4);
            #pragma unroll
            for (int i = 0; i < 4; ++i) {
                const float xv = xt[i][dk];
                aT[i][0] = fmaf(xv, wt0.x, aT[i][0]);
                aT[i][1] = fmaf(xv, wt0.y, aT[i][1]);
                aT[i][2] = fmaf(xv, wt0.z, aT[i][2]);
                aT[i][3] = fmaf(xv, wt0.w, aT[i][3]);
                aT[i][4] = fmaf(xv, wt1.x, aT[i][4]);
                aT[i][5] = fmaf(xv, wt1.y, aT[i][5]);
                aT[i][6] = fmaf(xv, wt1.z, aT[i][6]);
                aT[i][7] = fmaf(xv, wt1.w, aT[i][7]);
                const float yv = xl[i][dk];
                aL[i][0] = fmaf(yv, wl0.x, aL[i][0]);
                aL[i][1] = fmaf(yv, wl0.y, aL[i][1]);
                aL[i][2] = fmaf(yv, wl0.z, aL[i][2]);
                aL[i][3] = fmaf(yv, wl0.w, aL[i][3]);
                aL[i][4] = fmaf(yv, wl1.x, aL[i][4]);
                aL[i][5] = fmaf(yv, wl1.y, aL[i][5]);
                aL[i][6] = fmaf(yv, wl1.z, aL[i][6]);
                aL[i][7] = fmaf(yv, wl1.w, aL[i][7]);
            }
        }
    }

    // ---- cross-wave k-reduction (fixed order -> deterministic) ----
    // text partials
    #pragma unroll
    for (int i = 0; i < 4; ++i) {
        const int o = (ng * 4 + i) * 256 + c0;
        *reinterpret_cast<float4*>(&red[wave][o]) =
            make_float4(aT[i][0], aT[i][1], aT[i][2], aT[i][3]);
        *reinterpret_cast<float4*>(&red[wave][o + 4]) =
            make_float4(aT[i][4], aT[i][5], aT[i][6], aT[i][7]);
    }
    __syncthreads();
    float rT[8];
    #pragma unroll
    for (int i = 0; i < 8; ++i) {
        const int o = tid + 256 * i;
        rT[i] = (red[0][o] + red[1][o]) + (red[2][o] + red[3][o]);
    }
    __syncthreads();
    // label partials
    #pragma unroll
    for (int i = 0; i < 4; ++i) {
        const int o = (ng * 4 + i) * 256 + c0;
        *reinterpret_cast<float4*>(&red[wave][o]) =
            make_float4(aL[i][0], aL[i][1], aL[i][2], aL[i][3]);
        *reinterpret_cast<float4*>(&red[wave][o + 4]) =
            make_float4(aL[i][4], aL[i][5], aL[i][6], aL[i][7]);
    }
    __syncthreads();

    const float w0 = w_adap[0] * (1.0f / (float)NPG_);
    const float w1 = w_adap[1] * (1.0f / (float)NPG_);
    #pragma unroll
    for (int i = 0; i < 8; ++i) {
        const int o = tid + 256 * i;
        const float rL = (red[0][o] + red[1][o]) + (red[2][o] + red[3][o]);
        const float ht = rT[i] > 0.f ? rT[i] : 0.f;
        const float hl = rL    > 0.f ? rL    : 0.f;
        // o = i*256 + tid -> node base+i, col tid (coalesced)
        h_comb[(size_t)(base + i) * D_ + tid] = w0 * ht + w1 * hl;
    }
}

// ---------------- Kernel C: per-graph readout + MLP, 4 blocks per graph split Wout ----------------
__global__ __launch_bounds__(256) void graph_kernel(
    const float* __restrict__ h_comb,   // [NN, D]
    const float* __restrict__ W1,       // [D, D]
    const float* __restrict__ b1,       // [D]
    const float* __restrict__ Wout,     // [D, OUT]
    const float* __restrict__ bout,     // [OUT]
    float*       __restrict__ out)      // [BG, OUT]
{
    __shared__ float fused[D_];
    __shared__ float hrow[D_];

    const int bx   = blockIdx.x;
    const int b    = bx >> 2;
    const int part = bx & 3;
    const int tid  = threadIdx.x;

    float acc = 0.f;
    const float* __restrict__ basep = h_comb + (size_t)b * NPG_ * D_ + tid;
    #pragma unroll 8
    for (int n = 0; n < NPG_; ++n) acc += basep[(size_t)n * D_];
    fused[tid] = acc;
    __syncthreads();

    float a1 = b1[tid];
    for (int d = 0; d < D_; ++d)
        a1 = fmaf(fused[d], W1[(size_t)d * D_ + tid], a1);
    hrow[tid] = a1 > 0.f ? a1 : 0.f;
    __syncthreads();

    const int j = part * 256 + tid;
    float o = bout[j];
    for (int d = 0; d < D_; ++d)
        o = fmaf(hrow[d], Wout[(size_t)d * OUT_ + j], o);
    out[(size_t)b * OUT_ + j] = o;
}

extern "C" void kernel_launch(void* const* d_in, const int* in_sizes, int n_in,
                              void* d_out, int out_size, void* d_ws, size_t ws_size,
                              hipStream_t stream) {
    const int*   text_ids  = (const int*)  d_in[0];
    const int*   label_ids = (const int*)  d_in[1];
    const int*   text_len  = (const int*)  d_in[2];
    const int*   label_len = (const int*)  d_in[3];
    const float* word_emb  = (const float*)d_in[4];
    const float* label_emb = (const float*)d_in[5];
    const float* Wg_text   = (const float*)d_in[6];
    const float* Wg_label  = (const float*)d_in[7];
    const float* w_adap    = (const float*)d_in[8];
    const float* W1        = (const float*)d_in[9];
    const float* b1        = (const float*)d_in[10];
    const float* Wout      = (const float*)d_in[11];
    const float* bout      = (const float*)d_in[12];

    // ws layout: [0, 4MB) text_out (reused as h_comb: row-disjoint per block), [4MB, 8MB) label_out
    float* text_out  = (float*)d_ws;
    float* label_out = text_out + (size_t)NN * D_;
    float* h_comb    = text_out;
    float* out       = (float*)d_out;

    gather_kernel<<<NN, 256, 0, stream>>>(
        text_ids, label_ids, text_len, label_len,
        word_emb, label_emb, text_out, label_out);

    proj_kernel<<<NN / 8, 256, 0, stream>>>(
        text_out, label_out, Wg_text, Wg_label, w_adap, h_comb);

    graph_kernel<<<BG * 4, 256, 0, stream>>>(
        h_comb, W1, b1, Wout, bout, out);
}

// Round 5
// 89.750 us; speedup vs baseline: 1.3507x; 1.0712x over previous
//
#include <hip/hip_runtime.h>

#define NN      4096   // total nodes
#define BG      64     // graphs
#define NPG_    64     // nodes per graph
#define LT_     128
#define LL_     32
#define D_      256
#define OUT_    1024
#define NPBF    4      // nodes per block (fused kernel)

// ---------------- Fused gather + projection ----------------
// 1024 blocks x 256 thr, 4 nodes/block. Phases:
//  1. stage ids in LDS
//  2. 4-way wave-split ragged gathers (text mean, label sum) -> LDS reduce -> xT/xL
//  3. k-split projection (wave w owns k in [64w,64w+64)), lane owns 4 cols x 4 nodes
//  4. LDS k-reduce, relu, w_adap combine, coalesced h_comb write
// All reductions fixed-order -> deterministic.
__global__ __launch_bounds__(256, 4) void fused_kernel(
    const int*   __restrict__ text_ids,
    const int*   __restrict__ label_ids,
    const int*   __restrict__ text_len,
    const int*   __restrict__ label_len,
    const float* __restrict__ word_emb,
    const float* __restrict__ label_emb,
    const float* __restrict__ Wg_text,
    const float* __restrict__ Wg_label,
    const float* __restrict__ w_adap,
    float*       __restrict__ h_comb)     // [NN, D]
{
    __shared__ int   sIds[NPBF][LT_ + LL_];   // 2.5 KB
    __shared__ float red[4][NPBF * D_];       // 16 KB, time-multiplexed
    __shared__ float xT[NPBF][D_ + 8];        // 4.1 KB
    __shared__ float xL[NPBF][D_ + 8];        // 4.1 KB

    const int tid  = threadIdx.x;
    const int wave = tid >> 6;
    const int lane = tid & 63;
    const int base = blockIdx.x * NPBF;

    // ---- Phase 1: stage ids (coalesced) ----
    for (int idx = tid; idx < NPBF * LT_; idx += 256) {
        const int nd = idx >> 7, t = idx & (LT_ - 1);
        sIds[nd][t] = text_ids[(size_t)(base + nd) * LT_ + t];
    }
    if (tid < NPBF * LL_) {
        const int nd = tid >> 5, t = tid & (LL_ - 1);
        sIds[nd][LT_ + t] = label_ids[(size_t)(base + nd) * LL_ + t];
    }
    int lt[NPBF], ll[NPBF];
    #pragma unroll
    for (int nd = 0; nd < NPBF; ++nd) {
        lt[nd] = text_len[base + nd];
        ll[nd] = label_len[base + nd];
    }
    __syncthreads();

    // ---- Phase 2: ragged gathers (wave w takes rows l = w, w+4, ...) ----
    float4 aT[NPBF], aL[NPBF];
    {
        const float* __restrict__ bp = word_emb + (size_t)lane * 4;
        #pragma unroll
        for (int nd = 0; nd < NPBF; ++nd) {
            float4 a = make_float4(0.f, 0.f, 0.f, 0.f);
            #pragma unroll 8
            for (int l = wave; l < lt[nd]; l += 4) {
                const float4 v = *reinterpret_cast<const float4*>(
                    bp + (size_t)sIds[nd][l] * D_);
                a.x += v.x; a.y += v.y; a.z += v.z; a.w += v.w;
            }
            aT[nd] = a;
        }
    }
    {
        const float* __restrict__ bp = label_emb + (size_t)lane * 4;
        #pragma unroll
        for (int nd = 0; nd < NPBF; ++nd) {
            float4 a = make_float4(0.f, 0.f, 0.f, 0.f);
            #pragma unroll 8
            for (int l = wave; l < ll[nd]; l += 4) {
                const float4 v = *reinterpret_cast<const float4*>(
                    bp + (size_t)sIds[nd][LT_ + l] * D_);
                a.x += v.x; a.y += v.y; a.z += v.z; a.w += v.w;
            }
            aL[nd] = a;
        }
    }

    // text cross-wave reduce -> xT (divide by len here)
    #pragma unroll
    for (int nd = 0; nd < NPBF; ++nd)
        *reinterpret_cast<float4*>(&red[wave][nd * D_ + lane * 4]) = aT[nd];
    __syncthreads();
    #pragma unroll
    for (int i = 0; i < NPBF; ++i) {
        const int idx = tid + 256 * i;          // nd = i, col = tid
        const float v = (red[0][idx] + red[1][idx]) + (red[2][idx] + red[3][idx]);
        xT[i][tid] = v / (float)lt[i];
    }
    __syncthreads();
    // label cross-wave reduce -> xL (reuse red)
    #pragma unroll
    for (int nd = 0; nd < NPBF; ++nd)
        *reinterpret_cast<float4*>(&red[wave][nd * D_ + lane * 4]) = aL[nd];
    __syncthreads();
    #pragma unroll
    for (int i = 0; i < NPBF; ++i) {
        const int idx = tid + 256 * i;
        xL[i][tid] = (red[0][idx] + red[1][idx]) + (red[2][idx] + red[3][idx]);
    }
    __syncthreads();

    // ---- Phase 3: k-split projection ----
    float pT[NPBF][4], pL[NPBF][4];
    #pragma unroll
    for (int nd = 0; nd < NPBF; ++nd) {
        #pragma unroll
        for (int j = 0; j < 4; ++j) { pT[nd][j] = 0.f; pL[nd][j] = 0.f; }
    }
    const int c0 = lane * 4;
    const int k0 = wave * 64;

    for (int k4 = 0; k4 < 64; k4 += 4) {
        const int k = k0 + k4;
        float xt[NPBF][4], xl[NPBF][4];
        #pragma unroll
        for (int nd = 0; nd < NPBF; ++nd) {
            const float4 a = *reinterpret_cast<const float4*>(&xT[nd][k]);
            const float4 b = *reinterpret_cast<const float4*>(&xL[nd][k]);
            xt[nd][0] = a.x; xt[nd][1] = a.y; xt[nd][2] = a.z; xt[nd][3] = a.w;
            xl[nd][0] = b.x; xl[nd][1] = b.y; xl[nd][2] = b.z; xl[nd][3] = b.w;
        }
        #pragma unroll
        for (int dk = 0; dk < 4; ++dk) {
            const size_t ro = (size_t)(k + dk) * D_ + c0;
            const float4 wt = *reinterpret_cast<const float4*>(Wg_text  + ro);
            const float4 wl = *reinterpret_cast<const float4*>(Wg_label + ro);
            #pragma unroll
            for (int nd = 0; nd < NPBF; ++nd) {
                const float xv = xt[nd][dk];
                pT[nd][0] = fmaf(xv, wt.x, pT[nd][0]);
                pT[nd][1] = fmaf(xv, wt.y, pT[nd][1]);
                pT[nd][2] = fmaf(xv, wt.z, pT[nd][2]);
                pT[nd][3] = fmaf(xv, wt.w, pT[nd][3]);
                const float yv = xl[nd][dk];
                pL[nd][0] = fmaf(yv, wl.x, pL[nd][0]);
                pL[nd][1] = fmaf(yv, wl.y, pL[nd][1]);
                pL[nd][2] = fmaf(yv, wl.z, pL[nd][2]);
                pL[nd][3] = fmaf(yv, wl.w, pL[nd][3]);
            }
        }
    }

    // ---- Phase 4: k-reduction + combine (fixed order) ----
    #pragma unroll
    for (int nd = 0; nd < NPBF; ++nd)
        *reinterpret_cast<float4*>(&red[wave][nd * D_ + c0]) =
            make_float4(pT[nd][0], pT[nd][1], pT[nd][2], pT[nd][3]);
    __syncthreads();
    float rT[NPBF];
    #pragma unroll
    for (int i = 0; i < NPBF; ++i) {
        const int idx = tid + 256 * i;
        rT[i] = (red[0][idx] + red[1][idx]) + (red[2][idx] + red[3][idx]);
    }
    __syncthreads();
    #pragma unroll
    for (int nd = 0; nd < NPBF; ++nd)
        *reinterpret_cast<float4*>(&red[wave][nd * D_ + c0]) =
            make_float4(pL[nd][0], pL[nd][1], pL[nd][2], pL[nd][3]);
    __syncthreads();

    const float w0 = w_adap[0] * (1.0f / (float)NPG_);
    const float w1 = w_adap[1] * (1.0f / (float)NPG_);
    #pragma unroll
    for (int i = 0; i < NPBF; ++i) {
        const int idx = tid + 256 * i;
        const float rL = (red[0][idx] + red[1][idx]) + (red[2][idx] + red[3][idx]);
        const float ht = rT[i] > 0.f ? rT[i] : 0.f;
        const float hl = rL    > 0.f ? rL    : 0.f;
        h_comb[(size_t)(base + i) * D_ + tid] = w0 * ht + w1 * hl;
    }
}

// ---------------- Kernel C: per-graph readout + MLP, 4 blocks per graph split Wout ----------------
__global__ __launch_bounds__(256) void graph_kernel(
    const float* __restrict__ h_comb,   // [NN, D]
    const float* __restrict__ W1,       // [D, D]
    const float* __restrict__ b1,       // [D]
    const float* __restrict__ Wout,     // [D, OUT]
    const float* __restrict__ bout,     // [OUT]
    float*       __restrict__ out)      // [BG, OUT]
{
    __shared__ float fused[D_];
    __shared__ float hrow[D_];

    const int bx   = blockIdx.x;
    const int b    = bx >> 2;
    const int part = bx & 3;
    const int tid  = threadIdx.x;

    float acc = 0.f;
    const float* __restrict__ basep = h_comb + (size_t)b * NPG_ * D_ + tid;
    #pragma unroll 8
    for (int n = 0; n < NPG_; ++n) acc += basep[(size_t)n * D_];
    fused[tid] = acc;
    __syncthreads();

    float a1 = b1[tid];
    for (int d = 0; d < D_; ++d)
        a1 = fmaf(fused[d], W1[(size_t)d * D_ + tid], a1);
    hrow[tid] = a1 > 0.f ? a1 : 0.f;
    __syncthreads();

    const int j = part * 256 + tid;
    float o = bout[j];
    for (int d = 0; d < D_; ++d)
        o = fmaf(hrow[d], Wout[(size_t)d * OUT_ + j], o);
    out[(size_t)b * OUT_ + j] = o;
}

extern "C" void kernel_launch(void* const* d_in, const int* in_sizes, int n_in,
                              void* d_out, int out_size, void* d_ws, size_t ws_size,
                              hipStream_t stream) {
    const int*   text_ids  = (const int*)  d_in[0];
    const int*   label_ids = (const int*)  d_in[1];
    const int*   text_len  = (const int*)  d_in[2];
    const int*   label_len = (const int*)  d_in[3];
    const float* word_emb  = (const float*)d_in[4];
    const float* label_emb = (const float*)d_in[5];
    const float* Wg_text   = (const float*)d_in[6];
    const float* Wg_label  = (const float*)d_in[7];
    const float* w_adap    = (const float*)d_in[8];
    const float* W1        = (const float*)d_in[9];
    const float* b1        = (const float*)d_in[10];
    const float* Wout      = (const float*)d_in[11];
    const float* bout      = (const float*)d_in[12];

    float* h_comb = (float*)d_ws;      // 4 MiB scratch
    float* out    = (float*)d_out;

    fused_kernel<<<NN / NPBF, 256, 0, stream>>>(
        text_ids, label_ids, text_len, label_len,
        word_emb, label_emb, Wg_text, Wg_label, w_adap, h_comb);

    graph_kernel<<<BG * 4, 256, 0, stream>>>(
        h_comb, W1, b1, Wout, bout, out);
}